// Round 3
// baseline (157.135 us; speedup 1.0000x reference)
//
#include <hip/hip_runtime.h>

#define IN_F 8192
#define OUT_F 8192
#define BLOCK 256
#define WAVES_PER_BLOCK (BLOCK / 64)
#define N4 (IN_F / 4)   // 2048 float4 per row

typedef float v4f __attribute__((ext_vector_type(4)));

__global__ __launch_bounds__(BLOCK) void snn_fused_kernel(
    const float* __restrict__ x,        // [IN_F] spike_input
    const float* __restrict__ syn,      // [OUT_F, IN_F] synapse_states
    const float* __restrict__ mp,       // [OUT_F] membrane_potential
    const float* __restrict__ at,       // [OUT_F] adaptive_threshold
    const float* __restrict__ trace,    // [OUT_F, IN_F] eligibility_trace
    float* __restrict__ spikes_out,     // [OUT_F]
    float* __restrict__ vmem_out,       // [OUT_F]
    float* __restrict__ trace_out,      // [OUT_F, IN_F]
    float* __restrict__ thr_out)        // [OUT_F]
{
    const int wave = threadIdx.x >> 6;
    const int lane = threadIdx.x & 63;
    const int o    = blockIdx.x * WAVES_PER_BLOCK + wave;   // one row per wave

    const v4f* __restrict__ syn4 = reinterpret_cast<const v4f*>(syn + (size_t)o * IN_F);
    const v4f* __restrict__ x4   = reinterpret_cast<const v4f*>(x);

    // ---- Phase 1: masked row-sum  current[o] = sum_i (syn[o,i] > 50) * x[i]
    // 2048 v4f / 64 lanes = 32 iterations per lane; unroll 8 -> 16 loads in flight
    float partial = 0.0f;
    #pragma unroll 8
    for (int i = lane; i < N4; i += 64) {
        v4f s  = syn4[i];
        v4f xv = x4[i];
        partial += (s.x > 50.0f ? xv.x : 0.0f);
        partial += (s.y > 50.0f ? xv.y : 0.0f);
        partial += (s.z > 50.0f ? xv.z : 0.0f);
        partial += (s.w > 50.0f ? xv.w : 0.0f);
    }

    // wave butterfly reduce (no LDS, no barriers)
    #pragma unroll
    for (int off = 32; off > 0; off >>= 1)
        partial += __shfl_down(partial, off, 64);
    const float cur = __shfl(partial, 0, 64);   // broadcast to all 64 lanes

    // scalar LIF update — computed redundantly in all lanes (wave-uniform)
    const float v  = mp[o] * 0.8f + cur;
    const float a  = at[o];
    const float sp = (v >= a) ? 1.0f : 0.0f;
    if (lane == 0) {
        spikes_out[o] = sp;
        vmem_out[o]   = v * (1.0f - sp) * 0.2f;
        thr_out[o]    = fminf(fmaxf(a + (sp - 0.05f) * 0.1f, 0.5f), 10.0f);
    }

    // ---- Phase 2: trace update  clip(0.7*t + 3*spike*x, 0, 10)
    const float sp3 = sp * 3.0f;
    const v4f* __restrict__ tr4 = reinterpret_cast<const v4f*>(trace + (size_t)o * IN_F);
    v4f*       out4             = reinterpret_cast<v4f*>(trace_out + (size_t)o * IN_F);

    #pragma unroll 8
    for (int i = lane; i < N4; i += 64) {
        v4f t  = tr4[i];
        v4f xv = x4[i];
        v4f r;
        r.x = fminf(fmaxf(t.x * 0.7f + sp3 * xv.x, 0.0f), 10.0f);
        r.y = fminf(fmaxf(t.y * 0.7f + sp3 * xv.y, 0.0f), 10.0f);
        r.z = fminf(fmaxf(t.z * 0.7f + sp3 * xv.z, 0.0f), 10.0f);
        r.w = fminf(fmaxf(t.w * 0.7f + sp3 * xv.w, 0.0f), 10.0f);
        __builtin_nontemporal_store(r, &out4[i]);
    }
}

extern "C" void kernel_launch(void* const* d_in, const int* in_sizes, int n_in,
                              void* d_out, int out_size, void* d_ws, size_t ws_size,
                              hipStream_t stream) {
    const float* x     = (const float*)d_in[0];  // spike_input [8192]
    const float* syn   = (const float*)d_in[1];  // synapse_states [8192,8192]
    const float* mp    = (const float*)d_in[2];  // membrane_potential [8192]
    const float* at    = (const float*)d_in[3];  // adaptive_threshold [8192]
    const float* trace = (const float*)d_in[4];  // eligibility_trace [8192,8192]

    float* out        = (float*)d_out;
    float* spikes_out = out;                                           // [8192]
    float* vmem_out   = out + OUT_F;                                   // [8192]
    float* trace_out  = out + 2 * (size_t)OUT_F;                       // [8192*8192]
    float* thr_out    = out + 2 * (size_t)OUT_F + (size_t)OUT_F * IN_F;// [8192]

    snn_fused_kernel<<<OUT_F / WAVES_PER_BLOCK, BLOCK, 0, stream>>>(
        x, syn, mp, at, trace, spikes_out, vmem_out, trace_out, thr_out);
}